// Round 2
// baseline (981.596 us; speedup 1.0000x reference)
//
#include <hip/hip_runtime.h>
#include <cmath>

// SSIM fused kernel v2: separable 11x11 gaussian, 32x32 output tiles.
// Phase 1: horizontal conv (direct global float4 loads), write 5 planes to LDS.
// Phase 2: vertical conv + SSIM, ALL 256 threads (1 row x 4 cols each).

#define W 512
#define H 512
#define OWD 502
#define OHD 502
#define TILE 32
#define IN 42            // TILE + 10 halo rows
#define NVALID 12096192  // 48 * 502 * 502
#define NBLK (16 * 16 * 48)

struct Weights { float g[11]; };

__global__ __launch_bounds__(256, 4) void ssim_kernel(
    const float* __restrict__ x, const float* __restrict__ y,
    float* __restrict__ partial, float* __restrict__ accum, int use_atomic, Weights wt)
{
    __shared__ __align__(16) float hb[5][IN][TILE];
    __shared__ float wsum[4];

    const int tid = threadIdx.x;
    const int r0 = blockIdx.y * TILE;
    const int c0 = blockIdx.x * TILE;
    const size_t plane = (size_t)blockIdx.z * (W * H);
    const float* xp = x + plane;
    const float* yp = y + plane;

    // ---- Phase 1: horizontal pass. 42 rows x 8 col-groups (4 outputs each).
    for (int i = tid; i < IN * 8; i += 256) {
        const int r = i >> 3;
        const int cg = (i & 7) << 2;
        const int gr = r0 + r;
        float xv[16], yv[16];
        if (gr < H) {
            const float* xr = xp + (size_t)gr * W;
            const float* yr = yp + (size_t)gr * W;
            #pragma unroll
            for (int q = 0; q < 4; q++) {
                const int gc = c0 + cg + 4 * q;
                float4 a = make_float4(0.f, 0.f, 0.f, 0.f);
                float4 b = make_float4(0.f, 0.f, 0.f, 0.f);
                if (gc < W) {  // W%4==0 and gc%4==0 -> float4 fully in or out
                    a = *(const float4*)(xr + gc);
                    b = *(const float4*)(yr + gc);
                }
                xv[4*q+0] = a.x; xv[4*q+1] = a.y; xv[4*q+2] = a.z; xv[4*q+3] = a.w;
                yv[4*q+0] = b.x; yv[4*q+1] = b.y; yv[4*q+2] = b.z; yv[4*q+3] = b.w;
            }
        } else {
            #pragma unroll
            for (int j = 0; j < 16; j++) { xv[j] = 0.f; yv[j] = 0.f; }
        }
        float m1[4]  = {0.f, 0.f, 0.f, 0.f};
        float m2[4]  = {0.f, 0.f, 0.f, 0.f};
        float e11[4] = {0.f, 0.f, 0.f, 0.f};
        float e22[4] = {0.f, 0.f, 0.f, 0.f};
        float e12[4] = {0.f, 0.f, 0.f, 0.f};
        #pragma unroll
        for (int k = 0; k < 11; k++) {
            const float w = wt.g[k];
            #pragma unroll
            for (int j = 0; j < 4; j++) {
                const float xa = xv[j + k], ya = yv[j + k];
                m1[j]  += w * xa;
                m2[j]  += w * ya;
                e11[j] += w * (xa * xa);
                e22[j] += w * (ya * ya);
                e12[j] += w * (xa * ya);
            }
        }
        *(float4*)&hb[0][r][cg] = make_float4(m1[0], m1[1], m1[2], m1[3]);
        *(float4*)&hb[1][r][cg] = make_float4(m2[0], m2[1], m2[2], m2[3]);
        *(float4*)&hb[2][r][cg] = make_float4(e11[0], e11[1], e11[2], e11[3]);
        *(float4*)&hb[3][r][cg] = make_float4(e22[0], e22[1], e22[2], e22[3]);
        *(float4*)&hb[4][r][cg] = make_float4(e12[0], e12[1], e12[2], e12[3]);
    }
    __syncthreads();

    // ---- Phase 2: vertical pass + SSIM. All 256 threads: 1 row x 4 cols.
    float lsum = 0.f;
    {
        const int r = tid >> 3;          // output row within tile, 0..31
        const int cg = (tid & 7) << 2;   // col group
        float a1[4] = {0.f, 0.f, 0.f, 0.f};
        float a2[4] = {0.f, 0.f, 0.f, 0.f};
        float a3[4] = {0.f, 0.f, 0.f, 0.f};
        float a4[4] = {0.f, 0.f, 0.f, 0.f};
        float a5[4] = {0.f, 0.f, 0.f, 0.f};
        #pragma unroll
        for (int t = 0; t < 11; t++) {
            const float w = wt.g[t];
            const int row = r + t;
            float4 v0 = *(const float4*)&hb[0][row][cg];
            float4 v1 = *(const float4*)&hb[1][row][cg];
            float4 v2 = *(const float4*)&hb[2][row][cg];
            float4 v3 = *(const float4*)&hb[3][row][cg];
            float4 v4 = *(const float4*)&hb[4][row][cg];
            a1[0] += w * v0.x; a1[1] += w * v0.y; a1[2] += w * v0.z; a1[3] += w * v0.w;
            a2[0] += w * v1.x; a2[1] += w * v1.y; a2[2] += w * v1.z; a2[3] += w * v1.w;
            a3[0] += w * v2.x; a3[1] += w * v2.y; a3[2] += w * v2.z; a3[3] += w * v2.w;
            a4[0] += w * v3.x; a4[1] += w * v3.y; a4[2] += w * v3.z; a4[3] += w * v3.w;
            a5[0] += w * v4.x; a5[1] += w * v4.y; a5[2] += w * v4.z; a5[3] += w * v4.w;
        }
        const float C1 = 1e-4f;   // (0.01*1)^2
        const float C2 = 9e-4f;   // (0.03*1)^2
        const int orow = r0 + r;
        if (orow < OHD) {
            #pragma unroll
            for (int e = 0; e < 4; e++) {
                const int ocol = c0 + cg + e;
                if (ocol < OWD) {
                    const float mu1 = a1[e], mu2 = a2[e];
                    const float mu12 = mu1 * mu2;
                    const float mu1s = mu1 * mu1;
                    const float mu2s = mu2 * mu2;
                    const float s11 = a3[e] - mu1s;
                    const float s22 = a4[e] - mu2s;
                    const float s12 = a5[e] - mu12;
                    const float num = (2.f * mu12 + C1) * (2.f * s12 + C2);
                    const float den = (mu1s + mu2s + C1) * (s11 + s22 + C2);
                    lsum += num / den;
                }
            }
        }
    }

    // ---- Block reduction: wave shuffle, then LDS across the 4 waves.
    #pragma unroll
    for (int off = 32; off > 0; off >>= 1) lsum += __shfl_down(lsum, off, 64);
    const int wave = tid >> 6;
    if ((tid & 63) == 0) wsum[wave] = lsum;
    __syncthreads();
    if (tid == 0) {
        const float s = wsum[0] + wsum[1] + wsum[2] + wsum[3];
        const int bid = (blockIdx.z * 16 + blockIdx.y) * 16 + blockIdx.x;
        if (use_atomic) unsafeAtomicAdd(accum, s);
        else partial[bid] = s;
    }
}

__global__ __launch_bounds__(1024) void reduce_kernel(
    const float* __restrict__ partial, float* __restrict__ out)
{
    __shared__ float ws[16];
    float s = 0.f;
    for (int i = threadIdx.x; i < NBLK; i += 1024) s += partial[i];
    #pragma unroll
    for (int off = 32; off > 0; off >>= 1) s += __shfl_down(s, off, 64);
    const int wave = threadIdx.x >> 6;
    if ((threadIdx.x & 63) == 0) ws[wave] = s;
    __syncthreads();
    if (threadIdx.x == 0) {
        float t = 0.f;
        #pragma unroll
        for (int i = 0; i < 16; i++) t += ws[i];
        out[0] = t * (1.0f / (float)NVALID);
    }
}

__global__ void finalize_kernel(const float* __restrict__ accum, float* __restrict__ out) {
    out[0] = accum[0] * (1.0f / (float)NVALID);
}

extern "C" void kernel_launch(void* const* d_in, const int* in_sizes, int n_in,
                              void* d_out, int out_size, void* d_ws, size_t ws_size,
                              hipStream_t stream) {
    const float* x = (const float*)d_in[0];
    const float* y = (const float*)d_in[1];
    float* out = (float*)d_out;
    float* ws = (float*)d_ws;

    // Gaussian window, computed in double like the numpy reference, cast to f32.
    Weights wt;
    {
        double g[11], s = 0.0;
        for (int i = 0; i < 11; i++) {
            double d = (double)(i - 5);
            g[i] = exp(-(d * d) / (2.0 * 1.5 * 1.5));
            s += g[i];
        }
        for (int i = 0; i < 11; i++) wt.g[i] = (float)(g[i] / s);
    }

    dim3 grid(16, 16, 48);
    const int use_atomic = (ws_size < (size_t)NBLK * sizeof(float)) ? 1 : 0;
    if (use_atomic) {
        hipMemsetAsync(ws, 0, sizeof(float), stream);
        ssim_kernel<<<grid, 256, 0, stream>>>(x, y, ws, ws, 1, wt);
        finalize_kernel<<<1, 1, 0, stream>>>(ws, out);
    } else {
        ssim_kernel<<<grid, 256, 0, stream>>>(x, y, ws, ws, 0, wt);
        reduce_kernel<<<1, 1024, 0, stream>>>(ws, out);
    }
}

// Round 3
// 118.528 us; speedup vs baseline: 8.2816x; 8.2816x over previous
//
#include <hip/hip_runtime.h>
#include <cmath>

// SSIM fused kernel v3: v2 structure, but NO min-occupancy launch bound
// (the (256,4) bound capped VGPRs at 64 -> massive scratch spills -> 4.3 GB
// of HBM spill traffic). Default bounds gave 148 VGPR / zero spill in v1.

#define W 512
#define H 512
#define OWD 502
#define OHD 502
#define TILE 32
#define IN 42            // TILE + 10 halo rows
#define NVALID 12096192  // 48 * 502 * 502
#define NBLK (16 * 16 * 48)

struct Weights { float g[11]; };

__global__ __launch_bounds__(256) void ssim_kernel(
    const float* __restrict__ x, const float* __restrict__ y,
    float* __restrict__ partial, float* __restrict__ accum, int use_atomic, Weights wt)
{
    __shared__ __align__(16) float hb[5][IN][TILE];
    __shared__ float wsum[4];

    const int tid = threadIdx.x;
    const int r0 = blockIdx.y * TILE;
    const int c0 = blockIdx.x * TILE;
    const size_t plane = (size_t)blockIdx.z * (W * H);
    const float* xp = x + plane;
    const float* yp = y + plane;

    // ---- Phase 1: horizontal pass. 42 rows x 8 col-groups (4 outputs each).
    for (int i = tid; i < IN * 8; i += 256) {
        const int r = i >> 3;
        const int cg = (i & 7) << 2;
        const int gr = r0 + r;
        float xv[16], yv[16];
        if (gr < H) {
            const float* xr = xp + (size_t)gr * W;
            const float* yr = yp + (size_t)gr * W;
            #pragma unroll
            for (int q = 0; q < 4; q++) {
                const int gc = c0 + cg + 4 * q;
                float4 a = make_float4(0.f, 0.f, 0.f, 0.f);
                float4 b = make_float4(0.f, 0.f, 0.f, 0.f);
                if (gc < W) {  // W%4==0 and gc%4==0 -> float4 fully in or out
                    a = *(const float4*)(xr + gc);
                    b = *(const float4*)(yr + gc);
                }
                xv[4*q+0] = a.x; xv[4*q+1] = a.y; xv[4*q+2] = a.z; xv[4*q+3] = a.w;
                yv[4*q+0] = b.x; yv[4*q+1] = b.y; yv[4*q+2] = b.z; yv[4*q+3] = b.w;
            }
        } else {
            #pragma unroll
            for (int j = 0; j < 16; j++) { xv[j] = 0.f; yv[j] = 0.f; }
        }
        float m1[4]  = {0.f, 0.f, 0.f, 0.f};
        float m2[4]  = {0.f, 0.f, 0.f, 0.f};
        float e11[4] = {0.f, 0.f, 0.f, 0.f};
        float e22[4] = {0.f, 0.f, 0.f, 0.f};
        float e12[4] = {0.f, 0.f, 0.f, 0.f};
        #pragma unroll
        for (int k = 0; k < 11; k++) {
            const float w = wt.g[k];
            #pragma unroll
            for (int j = 0; j < 4; j++) {
                const float xa = xv[j + k], ya = yv[j + k];
                m1[j]  += w * xa;
                m2[j]  += w * ya;
                e11[j] += w * (xa * xa);
                e22[j] += w * (ya * ya);
                e12[j] += w * (xa * ya);
            }
        }
        *(float4*)&hb[0][r][cg] = make_float4(m1[0], m1[1], m1[2], m1[3]);
        *(float4*)&hb[1][r][cg] = make_float4(m2[0], m2[1], m2[2], m2[3]);
        *(float4*)&hb[2][r][cg] = make_float4(e11[0], e11[1], e11[2], e11[3]);
        *(float4*)&hb[3][r][cg] = make_float4(e22[0], e22[1], e22[2], e22[3]);
        *(float4*)&hb[4][r][cg] = make_float4(e12[0], e12[1], e12[2], e12[3]);
    }
    __syncthreads();

    // ---- Phase 2: vertical pass + SSIM. All 256 threads: 1 row x 4 cols.
    float lsum = 0.f;
    {
        const int r = tid >> 3;          // output row within tile, 0..31
        const int cg = (tid & 7) << 2;   // col group
        float a1[4] = {0.f, 0.f, 0.f, 0.f};
        float a2[4] = {0.f, 0.f, 0.f, 0.f};
        float a3[4] = {0.f, 0.f, 0.f, 0.f};
        float a4[4] = {0.f, 0.f, 0.f, 0.f};
        float a5[4] = {0.f, 0.f, 0.f, 0.f};
        #pragma unroll
        for (int t = 0; t < 11; t++) {
            const float w = wt.g[t];
            const int row = r + t;
            float4 v0 = *(const float4*)&hb[0][row][cg];
            float4 v1 = *(const float4*)&hb[1][row][cg];
            float4 v2 = *(const float4*)&hb[2][row][cg];
            float4 v3 = *(const float4*)&hb[3][row][cg];
            float4 v4 = *(const float4*)&hb[4][row][cg];
            a1[0] += w * v0.x; a1[1] += w * v0.y; a1[2] += w * v0.z; a1[3] += w * v0.w;
            a2[0] += w * v1.x; a2[1] += w * v1.y; a2[2] += w * v1.z; a2[3] += w * v1.w;
            a3[0] += w * v2.x; a3[1] += w * v2.y; a3[2] += w * v2.z; a3[3] += w * v2.w;
            a4[0] += w * v3.x; a4[1] += w * v3.y; a4[2] += w * v3.z; a4[3] += w * v3.w;
            a5[0] += w * v4.x; a5[1] += w * v4.y; a5[2] += w * v4.z; a5[3] += w * v4.w;
        }
        const float C1 = 1e-4f;   // (0.01*1)^2
        const float C2 = 9e-4f;   // (0.03*1)^2
        const int orow = r0 + r;
        if (orow < OHD) {
            #pragma unroll
            for (int e = 0; e < 4; e++) {
                const int ocol = c0 + cg + e;
                if (ocol < OWD) {
                    const float mu1 = a1[e], mu2 = a2[e];
                    const float mu12 = mu1 * mu2;
                    const float mu1s = mu1 * mu1;
                    const float mu2s = mu2 * mu2;
                    const float s11 = a3[e] - mu1s;
                    const float s22 = a4[e] - mu2s;
                    const float s12 = a5[e] - mu12;
                    const float num = (2.f * mu12 + C1) * (2.f * s12 + C2);
                    const float den = (mu1s + mu2s + C1) * (s11 + s22 + C2);
                    lsum += num / den;
                }
            }
        }
    }

    // ---- Block reduction: wave shuffle, then LDS across the 4 waves.
    #pragma unroll
    for (int off = 32; off > 0; off >>= 1) lsum += __shfl_down(lsum, off, 64);
    const int wave = tid >> 6;
    if ((tid & 63) == 0) wsum[wave] = lsum;
    __syncthreads();
    if (tid == 0) {
        const float s = wsum[0] + wsum[1] + wsum[2] + wsum[3];
        const int bid = (blockIdx.z * 16 + blockIdx.y) * 16 + blockIdx.x;
        if (use_atomic) unsafeAtomicAdd(accum, s);
        else partial[bid] = s;
    }
}

__global__ __launch_bounds__(1024) void reduce_kernel(
    const float* __restrict__ partial, float* __restrict__ out)
{
    __shared__ float ws[16];
    float s = 0.f;
    for (int i = threadIdx.x; i < NBLK; i += 1024) s += partial[i];
    #pragma unroll
    for (int off = 32; off > 0; off >>= 1) s += __shfl_down(s, off, 64);
    const int wave = threadIdx.x >> 6;
    if ((threadIdx.x & 63) == 0) ws[wave] = s;
    __syncthreads();
    if (threadIdx.x == 0) {
        float t = 0.f;
        #pragma unroll
        for (int i = 0; i < 16; i++) t += ws[i];
        out[0] = t * (1.0f / (float)NVALID);
    }
}

__global__ void finalize_kernel(const float* __restrict__ accum, float* __restrict__ out) {
    out[0] = accum[0] * (1.0f / (float)NVALID);
}

extern "C" void kernel_launch(void* const* d_in, const int* in_sizes, int n_in,
                              void* d_out, int out_size, void* d_ws, size_t ws_size,
                              hipStream_t stream) {
    const float* x = (const float*)d_in[0];
    const float* y = (const float*)d_in[1];
    float* out = (float*)d_out;
    float* ws = (float*)d_ws;

    // Gaussian window, computed in double like the numpy reference, cast to f32.
    Weights wt;
    {
        double g[11], s = 0.0;
        for (int i = 0; i < 11; i++) {
            double d = (double)(i - 5);
            g[i] = exp(-(d * d) / (2.0 * 1.5 * 1.5));
            s += g[i];
        }
        for (int i = 0; i < 11; i++) wt.g[i] = (float)(g[i] / s);
    }

    dim3 grid(16, 16, 48);
    const int use_atomic = (ws_size < (size_t)NBLK * sizeof(float)) ? 1 : 0;
    if (use_atomic) {
        hipMemsetAsync(ws, 0, sizeof(float), stream);
        ssim_kernel<<<grid, 256, 0, stream>>>(x, y, ws, ws, 1, wt);
        finalize_kernel<<<1, 1, 0, stream>>>(ws, out);
    } else {
        ssim_kernel<<<grid, 256, 0, stream>>>(x, y, ws, ws, 0, wt);
        reduce_kernel<<<1, 1024, 0, stream>>>(ws, out);
    }
}

// Round 4
// 92.172 us; speedup vs baseline: 10.6496x; 1.2859x over previous
//
#include <hip/hip_runtime.h>
#include <cmath>

// SSIM fused kernel v4: separable 11x11 gaussian.
// Tile = 32 cols x 64 rows (was 32x32). Phase 2 gives each thread a 2-row x
// 4-col patch: 12 halo'd rows of 5 planes -> 60 ds_read_b128 per 8 px
// (7.5/px, was 13.75/px). Vertical halo redundancy 74/64 = 1.16 (was 1.31).

#define W 512
#define H 512
#define OWD 502
#define OHD 502
#define TILEC 32
#define TILER 64
#define IN 74            // TILER + 10 halo rows
#define NVALID 12096192  // 48 * 502 * 502
#define NBLK (16 * 8 * 48)

struct Weights { float g[11]; };

__global__ __launch_bounds__(256) void ssim_kernel(
    const float* __restrict__ x, const float* __restrict__ y,
    float* __restrict__ partial, float* __restrict__ accum, int use_atomic, Weights wt)
{
    __shared__ __align__(16) float hb[5][IN][TILEC];
    __shared__ float wsum[4];

    const int tid = threadIdx.x;
    const int r0 = blockIdx.y * TILER;
    const int c0 = blockIdx.x * TILEC;
    const size_t plane = (size_t)blockIdx.z * (W * H);
    const float* xp = x + plane;
    const float* yp = y + plane;

    // ---- Phase 1: horizontal pass. 74 rows x 8 col-groups (4 outputs each).
    for (int i = tid; i < IN * 8; i += 256) {
        const int r = i >> 3;
        const int cg = (i & 7) << 2;
        const int gr = r0 + r;
        float xv[16], yv[16];
        if (gr < H) {
            const float* xr = xp + (size_t)gr * W;
            const float* yr = yp + (size_t)gr * W;
            #pragma unroll
            for (int q = 0; q < 4; q++) {
                const int gc = c0 + cg + 4 * q;
                float4 a = make_float4(0.f, 0.f, 0.f, 0.f);
                float4 b = make_float4(0.f, 0.f, 0.f, 0.f);
                if (gc < W) {  // W%4==0 and gc%4==0 -> float4 fully in or out
                    a = *(const float4*)(xr + gc);
                    b = *(const float4*)(yr + gc);
                }
                xv[4*q+0] = a.x; xv[4*q+1] = a.y; xv[4*q+2] = a.z; xv[4*q+3] = a.w;
                yv[4*q+0] = b.x; yv[4*q+1] = b.y; yv[4*q+2] = b.z; yv[4*q+3] = b.w;
            }
        } else {
            #pragma unroll
            for (int j = 0; j < 16; j++) { xv[j] = 0.f; yv[j] = 0.f; }
        }
        float m1[4]  = {0.f, 0.f, 0.f, 0.f};
        float m2[4]  = {0.f, 0.f, 0.f, 0.f};
        float e11[4] = {0.f, 0.f, 0.f, 0.f};
        float e22[4] = {0.f, 0.f, 0.f, 0.f};
        float e12[4] = {0.f, 0.f, 0.f, 0.f};
        #pragma unroll
        for (int k = 0; k < 11; k++) {
            const float w = wt.g[k];
            #pragma unroll
            for (int j = 0; j < 4; j++) {
                const float xa = xv[j + k], ya = yv[j + k];
                m1[j]  += w * xa;
                m2[j]  += w * ya;
                e11[j] += w * (xa * xa);
                e22[j] += w * (ya * ya);
                e12[j] += w * (xa * ya);
            }
        }
        *(float4*)&hb[0][r][cg] = make_float4(m1[0], m1[1], m1[2], m1[3]);
        *(float4*)&hb[1][r][cg] = make_float4(m2[0], m2[1], m2[2], m2[3]);
        *(float4*)&hb[2][r][cg] = make_float4(e11[0], e11[1], e11[2], e11[3]);
        *(float4*)&hb[3][r][cg] = make_float4(e22[0], e22[1], e22[2], e22[3]);
        *(float4*)&hb[4][r][cg] = make_float4(e12[0], e12[1], e12[2], e12[3]);
    }
    __syncthreads();

    // ---- Phase 2: vertical pass + SSIM. 256 threads: 2 rows x 4 cols each.
    float lsum = 0.f;
    {
        const int rp = tid >> 3;         // row pair 0..31 -> rows 2rp, 2rp+1
        const int cg = (tid & 7) << 2;   // col group
        float a[5][2][4];
        #pragma unroll
        for (int j = 0; j < 5; j++)
            #pragma unroll
            for (int rr = 0; rr < 2; rr++)
                #pragma unroll
                for (int e = 0; e < 4; e++) a[j][rr][e] = 0.f;

        #pragma unroll
        for (int t = 0; t < 12; t++) {
            const int row = 2 * rp + t;
            float4 v[5];
            #pragma unroll
            for (int j = 0; j < 5; j++) v[j] = *(const float4*)&hb[j][row][cg];
            if (t <= 10) {   // tap for output row 0 (compile-time)
                const float w = wt.g[t];
                #pragma unroll
                for (int j = 0; j < 5; j++) {
                    a[j][0][0] += w * v[j].x; a[j][0][1] += w * v[j].y;
                    a[j][0][2] += w * v[j].z; a[j][0][3] += w * v[j].w;
                }
            }
            if (t >= 1) {    // tap for output row 1 (compile-time)
                const float w = wt.g[t - 1];
                #pragma unroll
                for (int j = 0; j < 5; j++) {
                    a[j][1][0] += w * v[j].x; a[j][1][1] += w * v[j].y;
                    a[j][1][2] += w * v[j].z; a[j][1][3] += w * v[j].w;
                }
            }
        }

        const float C1 = 1e-4f;   // (0.01*1)^2
        const float C2 = 9e-4f;   // (0.03*1)^2
        #pragma unroll
        for (int rr = 0; rr < 2; rr++) {
            const int orow = r0 + 2 * rp + rr;
            if (orow < OHD) {
                #pragma unroll
                for (int e = 0; e < 4; e++) {
                    const int ocol = c0 + cg + e;
                    if (ocol < OWD) {
                        const float mu1 = a[0][rr][e], mu2 = a[1][rr][e];
                        const float mu12 = mu1 * mu2;
                        const float mu1s = mu1 * mu1;
                        const float mu2s = mu2 * mu2;
                        const float s11 = a[2][rr][e] - mu1s;
                        const float s22 = a[3][rr][e] - mu2s;
                        const float s12 = a[4][rr][e] - mu12;
                        const float num = (2.f * mu12 + C1) * (2.f * s12 + C2);
                        const float den = (mu1s + mu2s + C1) * (s11 + s22 + C2);
                        lsum += num / den;
                    }
                }
            }
        }
    }

    // ---- Block reduction: wave shuffle, then LDS across the 4 waves.
    #pragma unroll
    for (int off = 32; off > 0; off >>= 1) lsum += __shfl_down(lsum, off, 64);
    const int wave = tid >> 6;
    if ((tid & 63) == 0) wsum[wave] = lsum;
    __syncthreads();
    if (tid == 0) {
        const float s = wsum[0] + wsum[1] + wsum[2] + wsum[3];
        const int bid = (blockIdx.z * 8 + blockIdx.y) * 16 + blockIdx.x;
        if (use_atomic) unsafeAtomicAdd(accum, s);
        else partial[bid] = s;
    }
}

__global__ __launch_bounds__(1024) void reduce_kernel(
    const float* __restrict__ partial, float* __restrict__ out)
{
    __shared__ float ws[16];
    float s = 0.f;
    for (int i = threadIdx.x; i < NBLK; i += 1024) s += partial[i];
    #pragma unroll
    for (int off = 32; off > 0; off >>= 1) s += __shfl_down(s, off, 64);
    const int wave = threadIdx.x >> 6;
    if ((threadIdx.x & 63) == 0) ws[wave] = s;
    __syncthreads();
    if (threadIdx.x == 0) {
        float t = 0.f;
        #pragma unroll
        for (int i = 0; i < 16; i++) t += ws[i];
        out[0] = t * (1.0f / (float)NVALID);
    }
}

__global__ void finalize_kernel(const float* __restrict__ accum, float* __restrict__ out) {
    out[0] = accum[0] * (1.0f / (float)NVALID);
}

extern "C" void kernel_launch(void* const* d_in, const int* in_sizes, int n_in,
                              void* d_out, int out_size, void* d_ws, size_t ws_size,
                              hipStream_t stream) {
    const float* x = (const float*)d_in[0];
    const float* y = (const float*)d_in[1];
    float* out = (float*)d_out;
    float* ws = (float*)d_ws;

    // Gaussian window, computed in double like the numpy reference, cast to f32.
    Weights wt;
    {
        double g[11], s = 0.0;
        for (int i = 0; i < 11; i++) {
            double d = (double)(i - 5);
            g[i] = exp(-(d * d) / (2.0 * 1.5 * 1.5));
            s += g[i];
        }
        for (int i = 0; i < 11; i++) wt.g[i] = (float)(g[i] / s);
    }

    dim3 grid(16, 8, 48);
    const int use_atomic = (ws_size < (size_t)NBLK * sizeof(float)) ? 1 : 0;
    if (use_atomic) {
        hipMemsetAsync(ws, 0, sizeof(float), stream);
        ssim_kernel<<<grid, 256, 0, stream>>>(x, y, ws, ws, 1, wt);
        finalize_kernel<<<1, 1, 0, stream>>>(ws, out);
    } else {
        ssim_kernel<<<grid, 256, 0, stream>>>(x, y, ws, ws, 0, wt);
        reduce_kernel<<<1, 1024, 0, stream>>>(ws, out);
    }
}